// Round 2
// baseline (116.762 us; speedup 1.0000x reference)
//
#include <hip/hip_runtime.h>

#define SGRID 32
#define SGRID3 (SGRID * SGRID * SGRID)

// ---------------- prep: pad closest to float4, build affine mats, zero out ---
__global__ __launch_bounds__(256)
void prep_kernel(const float* __restrict__ output,
                 const float* __restrict__ closest,
                 float4* __restrict__ c4,
                 float* __restrict__ mats,   // B*6*12 floats
                 float* __restrict__ out,
                 int B) {
    int tid = blockIdx.x * blockDim.x + threadIdx.x;
    int total = B * SGRID3;
    int base = tid * 4;
    if (base + 3 < total) {
        const float4* src = (const float4*)closest;  // 4 cells = 12 floats = 3 float4
        float4 a = src[(size_t)tid * 3 + 0];
        float4 b = src[(size_t)tid * 3 + 1];
        float4 c = src[(size_t)tid * 3 + 2];
        c4[base + 0] = make_float4(a.x, a.y, a.z, 0.f);
        c4[base + 1] = make_float4(a.w, b.x, b.y, 0.f);
        c4[base + 2] = make_float4(b.z, b.w, c.x, 0.f);
        c4[base + 3] = make_float4(c.y, c.z, c.w, 0.f);
    }
    if (blockIdx.x == 0) {
        if (threadIdx.x == 0) out[0] = 0.f;
        if (threadIdx.x < B * 6) {
            int b = threadIdx.x / 6, i = threadIdx.x % 6;
            const float* p = output + b * 24 + i * 4;
            float m[12];
            if (i < 3) {
                // reflection: s = p + k*(n.p + d)*n, k = -2/|n|^2
                float a = p[0], bb = p[1], c = p[2], d = p[3];
                float k = -2.f / (a * a + bb * bb + c * c);
                m[0] = 1.f + k * a * a; m[1] = k * a * bb;      m[2] = k * a * c;       m[3] = k * d * a;
                m[4] = k * bb * a;      m[5] = 1.f + k * bb * bb; m[6] = k * bb * c;    m[7] = k * d * bb;
                m[8] = k * c * a;       m[9] = k * c * bb;      m[10] = 1.f + k * c * c; m[11] = k * d * c;
            } else {
                // rotation: q p q^-1 with q^-1 = conj/|q|  ->  M = R_unnorm(q)/|q|
                float w = p[0], x = p[1], y = p[2], z = p[3];
                float s = rsqrtf(w * w + x * x + y * y + z * z);
                m[0] = s * (w * w + x * x - y * y - z * z);
                m[1] = s * 2.f * (x * y - w * z);
                m[2] = s * 2.f * (x * z + w * y);
                m[3] = 0.f;
                m[4] = s * 2.f * (x * y + w * z);
                m[5] = s * (w * w - x * x + y * y - z * z);
                m[6] = s * 2.f * (y * z - w * x);
                m[7] = 0.f;
                m[8] = s * 2.f * (x * z - w * y);
                m[9] = s * 2.f * (y * z + w * x);
                m[10] = s * (w * w - x * x - y * y + z * z);
                m[11] = 0.f;
            }
            float* dst = mats + (size_t)threadIdx.x * 12;
#pragma unroll
            for (int j = 0; j < 12; j++) dst[j] = m[j];
        }
    }
}

// ---------------- main: 4 points/thread, 6 affine ops, float4 gathers --------
__global__ __launch_bounds__(256)
void sym_loss_fast(const float4* __restrict__ c4,
                   const float* __restrict__ mats,
                   const float* __restrict__ points,
                   float* __restrict__ out,
                   int N, int B, float invB) {
    const int i = blockIdx.x;
    int b, x;
    if (B == 16) {
        // XCD swizzle: round-robin dispatch puts block i on XCD i%8.
        // b = 2*(i&7) + bit -> each XCD serves exactly 2 batches (1 MB in L2).
        b = 2 * (i & 7) + ((i >> 3) & 1);
        x = i >> 4;
    } else {
        int npb = gridDim.x / B;
        b = i / npb;
        x = i - b * npb;
    }
    const int tid = x * blockDim.x + threadIdx.x;

    // wave-uniform scalar loads of the 6 affine mats
    const float* mb = mats + (size_t)b * 72;
    float M[72];
#pragma unroll
    for (int j = 0; j < 72; j++) M[j] = mb[j];

    const float* pb = points + (size_t)b * N * 3;
    const float4* cb = c4 + (size_t)b * SGRID3;

    float acc = 0.f;
    const int base = tid * 4;

    if (base + 3 < N) {
        const float4* pv = (const float4*)pb;
        float4 v0 = pv[(size_t)tid * 3 + 0];
        float4 v1 = pv[(size_t)tid * 3 + 1];
        float4 v2 = pv[(size_t)tid * 3 + 2];
        float px[4] = {v0.x, v0.w, v1.z, v2.y};
        float py[4] = {v0.y, v1.x, v1.w, v2.z};
        float pz[4] = {v0.z, v1.y, v2.x, v2.w};
#pragma unroll 2
        for (int k = 0; k < 4; k++) {
            float X = px[k], Y = py[k], Z = pz[k];
            float sx[6], sy[6], sz[6];
            float4 g[6];
#pragma unroll
            for (int op = 0; op < 6; op++) {
                const float* m = &M[op * 12];
                sx[op] = fmaf(m[0], X, fmaf(m[1], Y, fmaf(m[2], Z, m[3])));
                sy[op] = fmaf(m[4], X, fmaf(m[5], Y, fmaf(m[6], Z, m[7])));
                sz[op] = fmaf(m[8], X, fmaf(m[9], Y, fmaf(m[10], Z, m[11])));
                float cx = fminf(fmaxf(sx[op], 0.f), 32.f);
                float cy = fminf(fmaxf(sy[op], 0.f), 32.f);
                float cz = fminf(fmaxf(sz[op], 0.f), 32.f);
                int ix = min((int)cx, 31);
                int iy = min((int)cy, 31);
                int iz = min((int)cz, 31);
                int flat = (ix << 10) | (iy << 5) | iz;
                g[op] = cb[flat];
            }
#pragma unroll
            for (int op = 0; op < 6; op++) {
                float dx = sx[op] - g[op].x;
                float dy = sy[op] - g[op].y;
                float dz = sz[op] - g[op].z;
                acc += __builtin_amdgcn_sqrtf(fmaf(dx, dx, fmaf(dy, dy, dz * dz)));
            }
        }
    } else if (base < N) {
        for (int k = 0; k < N - base; k++) {
            float X = pb[(size_t)(base + k) * 3 + 0];
            float Y = pb[(size_t)(base + k) * 3 + 1];
            float Z = pb[(size_t)(base + k) * 3 + 2];
#pragma unroll
            for (int op = 0; op < 6; op++) {
                const float* m = &M[op * 12];
                float sx = fmaf(m[0], X, fmaf(m[1], Y, fmaf(m[2], Z, m[3])));
                float sy = fmaf(m[4], X, fmaf(m[5], Y, fmaf(m[6], Z, m[7])));
                float sz = fmaf(m[8], X, fmaf(m[9], Y, fmaf(m[10], Z, m[11])));
                float cx = fminf(fmaxf(sx, 0.f), 32.f);
                float cy = fminf(fmaxf(sy, 0.f), 32.f);
                float cz = fminf(fmaxf(sz, 0.f), 32.f);
                int ix = min((int)cx, 31);
                int iy = min((int)cy, 31);
                int iz = min((int)cz, 31);
                float4 g = cb[(ix << 10) | (iy << 5) | iz];
                float dx = sx - g.x, dy = sy - g.y, dz = sz - g.z;
                acc += __builtin_amdgcn_sqrtf(fmaf(dx, dx, fmaf(dy, dy, dz * dz)));
            }
        }
    }

#pragma unroll
    for (int off = 32; off > 0; off >>= 1)
        acc += __shfl_down(acc, off, 64);

    __shared__ float sacc[4];
    int lane = threadIdx.x & 63;
    int wid = threadIdx.x >> 6;
    if (lane == 0) sacc[wid] = acc;
    __syncthreads();
    if (threadIdx.x == 0) {
        atomicAdd(out, (sacc[0] + sacc[1] + sacc[2] + sacc[3]) * invB);
    }
}

// ---------------- fallback (ws too small): round-1 kernel -------------------
__global__ void zero_out_kernel(float* out) { out[0] = 0.0f; }

__device__ __forceinline__ float dist_to_cell3(float sx, float sy, float sz,
                                               const float* __restrict__ cb) {
    float cx = fminf(fmaxf(sx, 0.0f), 32.0f);
    float cy = fminf(fmaxf(sy, 0.0f), 32.0f);
    float cz = fminf(fmaxf(sz, 0.0f), 32.0f);
    int ix = min((int)cx, 31);
    int iy = min((int)cy, 31);
    int iz = min((int)cz, 31);
    int flat = (ix << 10) | (iy << 5) | iz;
    const float* c = cb + (size_t)flat * 3;
    float dx = sx - c[0], dy = sy - c[1], dz = sz - c[2];
    return __builtin_amdgcn_sqrtf(fmaf(dx, dx, fmaf(dy, dy, dz * dz)));
}

__launch_bounds__(256)
__global__ void sym_loss_kernel(const float* __restrict__ output,
                                const float* __restrict__ points,
                                const float* __restrict__ closest,
                                float* __restrict__ out,
                                int N, float invB) {
    const int b = blockIdx.y;
    const int tid = blockIdx.x * blockDim.x + threadIdx.x;
    const float* prm = output + (size_t)b * 24;
    float pn[3][4], inv_nn[3], qt[3][4], qinvn[3];
#pragma unroll
    for (int i = 0; i < 3; i++) {
        pn[i][0] = prm[i * 4 + 0]; pn[i][1] = prm[i * 4 + 1];
        pn[i][2] = prm[i * 4 + 2]; pn[i][3] = prm[i * 4 + 3];
        inv_nn[i] = 1.0f / (pn[i][0] * pn[i][0] + pn[i][1] * pn[i][1] + pn[i][2] * pn[i][2]);
        qt[i][0] = prm[12 + i * 4 + 0]; qt[i][1] = prm[12 + i * 4 + 1];
        qt[i][2] = prm[12 + i * 4 + 2]; qt[i][3] = prm[12 + i * 4 + 3];
        qinvn[i] = rsqrtf(qt[i][0] * qt[i][0] + qt[i][1] * qt[i][1] +
                          qt[i][2] * qt[i][2] + qt[i][3] * qt[i][3]);
    }
    const float* pb = points + (size_t)b * N * 3;
    const float* cb = closest + (size_t)b * SGRID3 * 3;
    float acc = 0.0f;
    const int base = tid * 4;
    float px[4], py[4], pz[4];
    int npts = 0;
    if (base + 3 < N) {
        const float4* pv = (const float4*)pb;
        float4 v0 = pv[(size_t)tid * 3 + 0];
        float4 v1 = pv[(size_t)tid * 3 + 1];
        float4 v2 = pv[(size_t)tid * 3 + 2];
        px[0] = v0.x; py[0] = v0.y; pz[0] = v0.z;
        px[1] = v0.w; py[1] = v1.x; pz[1] = v1.y;
        px[2] = v1.z; py[2] = v1.w; pz[2] = v2.x;
        px[3] = v2.y; py[3] = v2.z; pz[3] = v2.w;
        npts = 4;
    } else if (base < N) {
        npts = N - base;
        for (int k = 0; k < npts; k++) {
            px[k] = pb[(size_t)(base + k) * 3 + 0];
            py[k] = pb[(size_t)(base + k) * 3 + 1];
            pz[k] = pb[(size_t)(base + k) * 3 + 2];
        }
    }
#pragma unroll
    for (int k = 0; k < 4; k++) {
        if (k >= npts) break;
        float x = px[k], y = py[k], z = pz[k];
#pragma unroll
        for (int i = 0; i < 3; i++) {
            float nx = pn[i][0], ny = pn[i][1], nz = pn[i][2];
            float dis = (nx * x + ny * y + nz * z + pn[i][3]) * inv_nn[i];
            float t = 2.0f * dis;
            acc += dist_to_cell3(x - t * nx, y - t * ny, z - t * nz, cb);
        }
#pragma unroll
        for (int i = 0; i < 3; i++) {
            float rw = qt[i][0], rx = qt[i][1], ry = qt[i][2], rz = qt[i][3];
            float tw = -(rx * x + ry * y + rz * z);
            float tx = rw * x + (ry * z - rz * y);
            float ty = rw * y + (rz * x - rx * z);
            float tz = rw * z + (rx * y - ry * x);
            float n = qinvn[i];
            float ox = (-tw * rx + rw * tx + (ry * tz - rz * ty)) * n;
            float oy = (-tw * ry + rw * ty + (rz * tx - rx * tz)) * n;
            float oz = (-tw * rz + rw * tz + (rx * ty - ry * tx)) * n;
            acc += dist_to_cell3(ox, oy, oz, cb);
        }
    }
#pragma unroll
    for (int off = 32; off > 0; off >>= 1)
        acc += __shfl_down(acc, off, 64);
    __shared__ float sacc[4];
    int lane = threadIdx.x & 63;
    int wid = threadIdx.x >> 6;
    if (lane == 0) sacc[wid] = acc;
    __syncthreads();
    if (threadIdx.x == 0)
        atomicAdd(out, (sacc[0] + sacc[1] + sacc[2] + sacc[3]) * invB);
}

extern "C" void kernel_launch(void* const* d_in, const int* in_sizes, int n_in,
                              void* d_out, int out_size, void* d_ws, size_t ws_size,
                              hipStream_t stream) {
    const float* output = (const float*)d_in[0];
    const float* points = (const float*)d_in[1];
    const float* closest = (const float*)d_in[2];
    float* out = (float*)d_out;

    int B = in_sizes[0] / 24;
    int N = in_sizes[1] / (3 * B);

    size_t c4_bytes = (size_t)B * SGRID3 * 16;
    size_t mats_bytes = (size_t)B * 72 * 4;

    if (ws_size >= c4_bytes + mats_bytes) {
        float4* c4 = (float4*)d_ws;
        float* mats = (float*)((char*)d_ws + c4_bytes);
        int pad_threads = (B * SGRID3) / 4;
        int pad_blocks = (pad_threads + 255) / 256;
        prep_kernel<<<pad_blocks, 256, 0, stream>>>(output, closest, c4, mats, out, B);
        int npb = (N + 1023) / 1024;  // blocks per batch (256 thr x 4 pts)
        sym_loss_fast<<<B * npb, 256, 0, stream>>>(c4, mats, points, out, N, B,
                                                   1.0f / (float)B);
    } else {
        zero_out_kernel<<<1, 1, 0, stream>>>(out);
        int gx = (N + 1023) / 1024;
        dim3 grid(gx, B);
        sym_loss_kernel<<<grid, 256, 0, stream>>>(output, points, closest, out,
                                                  N, 1.0f / (float)B);
    }
}

// Round 3
// 94.920 us; speedup vs baseline: 1.2301x; 1.2301x over previous
//
#include <hip/hip_runtime.h>

#define SGRID 32
#define SGRID3 (SGRID * SGRID * SGRID)   // 32768 cells
#define QSCALE 31.96875f                  // 1023/32
#define DQSCALE (32.0f / 1023.0f)

// ---------------- prep: quantize closest -> 10:10:10 u32, build mats, zero out
__global__ __launch_bounds__(256)
void prep_kernel(const float* __restrict__ output,
                 const float* __restrict__ closest,
                 unsigned int* __restrict__ tbl,   // B * 32768
                 float* __restrict__ mats,         // B * 72
                 float* __restrict__ out,
                 int B) {
    int tid = blockIdx.x * blockDim.x + threadIdx.x;
    int total = B * SGRID3;
    int base = tid * 4;
    if (base + 3 < total) {
        const float4* src = (const float4*)closest;  // 4 cells = 12 floats
        float4 a = src[(size_t)tid * 3 + 0];
        float4 b = src[(size_t)tid * 3 + 1];
        float4 c = src[(size_t)tid * 3 + 2];
        float cx[4] = {a.x, a.w, b.z, c.y};
        float cy[4] = {a.y, b.x, b.w, c.z};
        float cz[4] = {a.z, b.y, c.x, c.w};
        uint4 q;
        unsigned int* qp = (unsigned int*)&q;
#pragma unroll
        for (int k = 0; k < 4; k++) {
            unsigned int qx = min((unsigned int)(fmaxf(cx[k], 0.f) * QSCALE + 0.5f), 1023u);
            unsigned int qy = min((unsigned int)(fmaxf(cy[k], 0.f) * QSCALE + 0.5f), 1023u);
            unsigned int qz = min((unsigned int)(fmaxf(cz[k], 0.f) * QSCALE + 0.5f), 1023u);
            qp[k] = qx | (qy << 10) | (qz << 20);
        }
        *((uint4*)(tbl + base)) = q;
    }
    if (blockIdx.x == 0) {
        if (threadIdx.x == 0) out[0] = 0.f;
        if (threadIdx.x < B * 6) {
            int b = threadIdx.x / 6, i = threadIdx.x % 6;
            const float* p = output + b * 24 + i * 4;
            float m[12];
            if (i < 3) {
                float a = p[0], bb = p[1], c = p[2], d = p[3];
                float k = -2.f / (a * a + bb * bb + c * c);
                m[0] = 1.f + k * a * a;  m[1] = k * a * bb;       m[2] = k * a * c;        m[3] = k * d * a;
                m[4] = k * bb * a;       m[5] = 1.f + k * bb * bb; m[6] = k * bb * c;      m[7] = k * d * bb;
                m[8] = k * c * a;        m[9] = k * c * bb;       m[10] = 1.f + k * c * c; m[11] = k * d * c;
            } else {
                float w = p[0], x = p[1], y = p[2], z = p[3];
                float s = rsqrtf(w * w + x * x + y * y + z * z);
                m[0] = s * (w * w + x * x - y * y - z * z);
                m[1] = s * 2.f * (x * y - w * z);
                m[2] = s * 2.f * (x * z + w * y);
                m[3] = 0.f;
                m[4] = s * 2.f * (x * y + w * z);
                m[5] = s * (w * w - x * x + y * y - z * z);
                m[6] = s * 2.f * (y * z - w * x);
                m[7] = 0.f;
                m[8] = s * 2.f * (x * z - w * y);
                m[9] = s * 2.f * (y * z + w * x);
                m[10] = s * (w * w - x * x - y * y + z * z);
                m[11] = 0.f;
            }
            float* dst = mats + (size_t)threadIdx.x * 12;
#pragma unroll
            for (int j = 0; j < 12; j++) dst[j] = m[j];
        }
    }
}

// ---------------- main: table staged in 128 KB LDS, ds_read_b32 gathers -----
__global__ __launch_bounds__(1024)
void sym_loss_lds(const unsigned int* __restrict__ tbl,
                  const float* __restrict__ mats,
                  const float* __restrict__ points,
                  float* __restrict__ out,
                  int N, int B, int bpb, float invB) {
    __shared__ unsigned int sT[SGRID3];   // 128 KB
    __shared__ float sred[16];

    const int i = blockIdx.x;
    int b, x;
    if (B == 16 && (gridDim.x & 15) == 0) {
        // XCD swizzle: block i lands on XCD i%8 -> 2 batches per XCD
        b = 2 * (i & 7) + ((i >> 3) & 1);
        x = i >> 4;
    } else {
        b = i / bpb;
        x = i - b * bpb;
    }

    // stage table: 8192 uint4 across 1024 threads = 8 x 16B each
    {
        const uint4* src = (const uint4*)(tbl + (size_t)b * SGRID3);
        uint4* dst = (uint4*)sT;
#pragma unroll
        for (int j = 0; j < SGRID3 / 4 / 1024; j++)
            dst[j * 1024 + threadIdx.x] = src[j * 1024 + threadIdx.x];
    }

    // wave-uniform affine mats (6 x 3x4)
    const float* mb = mats + (size_t)b * 72;
    float M[72];
#pragma unroll
    for (int j = 0; j < 72; j++) M[j] = mb[j];

    __syncthreads();

    const float* pb = points + (size_t)b * N * 3;
    const float4* pv = (const float4*)pb;
    float acc = 0.f;

    // block handles 2*blockDim quads (quad = 4 points = 3 float4)
    const int qpb = 2 * blockDim.x;
#pragma unroll
    for (int pass = 0; pass < 2; pass++) {
        int q = x * qpb + pass * blockDim.x + threadIdx.x;
        int base = q * 4;
        if (base + 3 < N) {
            float4 v0 = pv[(size_t)q * 3 + 0];
            float4 v1 = pv[(size_t)q * 3 + 1];
            float4 v2 = pv[(size_t)q * 3 + 2];
            float px[4] = {v0.x, v0.w, v1.z, v2.y};
            float py[4] = {v0.y, v1.x, v1.w, v2.z};
            float pz[4] = {v0.z, v1.y, v2.x, v2.w};
#pragma unroll 2
            for (int k = 0; k < 4; k++) {
                float X = px[k], Y = py[k], Z = pz[k];
                float sx[6], sy[6], sz[6];
                unsigned int g[6];
#pragma unroll
                for (int op = 0; op < 6; op++) {
                    const float* m = &M[op * 12];
                    sx[op] = fmaf(m[0], X, fmaf(m[1], Y, fmaf(m[2], Z, m[3])));
                    sy[op] = fmaf(m[4], X, fmaf(m[5], Y, fmaf(m[6], Z, m[7])));
                    sz[op] = fmaf(m[8], X, fmaf(m[9], Y, fmaf(m[10], Z, m[11])));
                    float cx = fminf(fmaxf(sx[op], 0.f), 32.f);
                    float cy = fminf(fmaxf(sy[op], 0.f), 32.f);
                    float cz = fminf(fmaxf(sz[op], 0.f), 32.f);
                    int ix = min((int)cx, 31);
                    int iy = min((int)cy, 31);
                    int iz = min((int)cz, 31);
                    g[op] = sT[(ix << 10) | (iy << 5) | iz];
                }
#pragma unroll
                for (int op = 0; op < 6; op++) {
                    float gx = (float)(g[op] & 1023u) * DQSCALE;
                    float gy = (float)((g[op] >> 10) & 1023u) * DQSCALE;
                    float gz = (float)(g[op] >> 20) * DQSCALE;
                    float dx = sx[op] - gx;
                    float dy = sy[op] - gy;
                    float dz = sz[op] - gz;
                    acc += __builtin_amdgcn_sqrtf(fmaf(dx, dx, fmaf(dy, dy, dz * dz)));
                }
            }
        } else if (base < N) {
            for (int k = 0; k < N - base; k++) {
                float X = pb[(size_t)(base + k) * 3 + 0];
                float Y = pb[(size_t)(base + k) * 3 + 1];
                float Z = pb[(size_t)(base + k) * 3 + 2];
#pragma unroll
                for (int op = 0; op < 6; op++) {
                    const float* m = &M[op * 12];
                    float ssx = fmaf(m[0], X, fmaf(m[1], Y, fmaf(m[2], Z, m[3])));
                    float ssy = fmaf(m[4], X, fmaf(m[5], Y, fmaf(m[6], Z, m[7])));
                    float ssz = fmaf(m[8], X, fmaf(m[9], Y, fmaf(m[10], Z, m[11])));
                    float cx = fminf(fmaxf(ssx, 0.f), 32.f);
                    float cy = fminf(fmaxf(ssy, 0.f), 32.f);
                    float cz = fminf(fmaxf(ssz, 0.f), 32.f);
                    int ix = min((int)cx, 31);
                    int iy = min((int)cy, 31);
                    int iz = min((int)cz, 31);
                    unsigned int gg = sT[(ix << 10) | (iy << 5) | iz];
                    float gx = (float)(gg & 1023u) * DQSCALE;
                    float gy = (float)((gg >> 10) & 1023u) * DQSCALE;
                    float gz = (float)(gg >> 20) * DQSCALE;
                    float dx = ssx - gx, dy = ssy - gy, dz = ssz - gz;
                    acc += __builtin_amdgcn_sqrtf(fmaf(dx, dx, fmaf(dy, dy, dz * dz)));
                }
            }
        }
    }

    // reduce: wave64 shuffle -> LDS -> one atomic per block
#pragma unroll
    for (int off = 32; off > 0; off >>= 1)
        acc += __shfl_down(acc, off, 64);

    int lane = threadIdx.x & 63;
    int wid = threadIdx.x >> 6;
    if (lane == 0) sred[wid] = acc;
    __syncthreads();
    if (threadIdx.x == 0) {
        float s = 0.f;
#pragma unroll
        for (int w = 0; w < 16; w++) s += sred[w];
        atomicAdd(out, s * invB);
    }
}

// ---------------- fallback (ws too small): direct-gather kernel -------------
__global__ void zero_out_kernel(float* out) { out[0] = 0.0f; }

__launch_bounds__(256)
__global__ void sym_loss_kernel(const float* __restrict__ output,
                                const float* __restrict__ points,
                                const float* __restrict__ closest,
                                float* __restrict__ out,
                                int N, float invB) {
    const int b = blockIdx.y;
    const int tid = blockIdx.x * blockDim.x + threadIdx.x;
    const float* prm = output + (size_t)b * 24;
    float pn[3][4], inv_nn[3], qt[3][4], qinvn[3];
#pragma unroll
    for (int i = 0; i < 3; i++) {
        pn[i][0] = prm[i * 4 + 0]; pn[i][1] = prm[i * 4 + 1];
        pn[i][2] = prm[i * 4 + 2]; pn[i][3] = prm[i * 4 + 3];
        inv_nn[i] = 1.0f / (pn[i][0] * pn[i][0] + pn[i][1] * pn[i][1] + pn[i][2] * pn[i][2]);
        qt[i][0] = prm[12 + i * 4 + 0]; qt[i][1] = prm[12 + i * 4 + 1];
        qt[i][2] = prm[12 + i * 4 + 2]; qt[i][3] = prm[12 + i * 4 + 3];
        qinvn[i] = rsqrtf(qt[i][0] * qt[i][0] + qt[i][1] * qt[i][1] +
                          qt[i][2] * qt[i][2] + qt[i][3] * qt[i][3]);
    }
    const float* pb = points + (size_t)b * N * 3;
    const float* cb = closest + (size_t)b * SGRID3 * 3;
    float acc = 0.0f;
    const int base = tid * 4;
    float px[4], py[4], pz[4];
    int npts = 0;
    if (base + 3 < N) {
        const float4* pv = (const float4*)pb;
        float4 v0 = pv[(size_t)tid * 3 + 0];
        float4 v1 = pv[(size_t)tid * 3 + 1];
        float4 v2 = pv[(size_t)tid * 3 + 2];
        px[0] = v0.x; py[0] = v0.y; pz[0] = v0.z;
        px[1] = v0.w; py[1] = v1.x; pz[1] = v1.y;
        px[2] = v1.z; py[2] = v1.w; pz[2] = v2.x;
        px[3] = v2.y; py[3] = v2.z; pz[3] = v2.w;
        npts = 4;
    } else if (base < N) {
        npts = N - base;
        for (int k = 0; k < npts; k++) {
            px[k] = pb[(size_t)(base + k) * 3 + 0];
            py[k] = pb[(size_t)(base + k) * 3 + 1];
            pz[k] = pb[(size_t)(base + k) * 3 + 2];
        }
    }
#pragma unroll
    for (int k = 0; k < 4; k++) {
        if (k >= npts) break;
        float x = px[k], y = py[k], z = pz[k];
#pragma unroll
        for (int i = 0; i < 3; i++) {
            float nx = pn[i][0], ny = pn[i][1], nz = pn[i][2];
            float dis = (nx * x + ny * y + nz * z + pn[i][3]) * inv_nn[i];
            float t = 2.0f * dis;
            float sx = x - t * nx, sy = y - t * ny, sz = z - t * nz;
            float cx = fminf(fmaxf(sx, 0.f), 32.f);
            float cy = fminf(fmaxf(sy, 0.f), 32.f);
            float cz = fminf(fmaxf(sz, 0.f), 32.f);
            const float* c = cb + (size_t)(((min((int)cx, 31)) << 10) |
                                           ((min((int)cy, 31)) << 5) |
                                           (min((int)cz, 31))) * 3;
            float dx = sx - c[0], dy = sy - c[1], dz = sz - c[2];
            acc += __builtin_amdgcn_sqrtf(fmaf(dx, dx, fmaf(dy, dy, dz * dz)));
        }
#pragma unroll
        for (int i = 0; i < 3; i++) {
            float rw = qt[i][0], rx = qt[i][1], ry = qt[i][2], rz = qt[i][3];
            float tw = -(rx * x + ry * y + rz * z);
            float tx = rw * x + (ry * z - rz * y);
            float ty = rw * y + (rz * x - rx * z);
            float tz = rw * z + (rx * y - ry * x);
            float n = qinvn[i];
            float ox = (-tw * rx + rw * tx + (ry * tz - rz * ty)) * n;
            float oy = (-tw * ry + rw * ty + (rz * tx - rx * tz)) * n;
            float oz = (-tw * rz + rw * tz + (rx * ty - ry * tx)) * n;
            float cx = fminf(fmaxf(ox, 0.f), 32.f);
            float cy = fminf(fmaxf(oy, 0.f), 32.f);
            float cz = fminf(fmaxf(oz, 0.f), 32.f);
            const float* c = cb + (size_t)(((min((int)cx, 31)) << 10) |
                                           ((min((int)cy, 31)) << 5) |
                                           (min((int)cz, 31))) * 3;
            float dx = ox - c[0], dy = oy - c[1], dz = oz - c[2];
            acc += __builtin_amdgcn_sqrtf(fmaf(dx, dx, fmaf(dy, dy, dz * dz)));
        }
    }
#pragma unroll
    for (int off = 32; off > 0; off >>= 1)
        acc += __shfl_down(acc, off, 64);
    __shared__ float sacc[4];
    int lane = threadIdx.x & 63;
    int wid = threadIdx.x >> 6;
    if (lane == 0) sacc[wid] = acc;
    __syncthreads();
    if (threadIdx.x == 0)
        atomicAdd(out, (sacc[0] + sacc[1] + sacc[2] + sacc[3]) * invB);
}

extern "C" void kernel_launch(void* const* d_in, const int* in_sizes, int n_in,
                              void* d_out, int out_size, void* d_ws, size_t ws_size,
                              hipStream_t stream) {
    const float* output = (const float*)d_in[0];
    const float* points = (const float*)d_in[1];
    const float* closest = (const float*)d_in[2];
    float* out = (float*)d_out;

    int B = in_sizes[0] / 24;
    int N = in_sizes[1] / (3 * B);

    size_t tbl_bytes = (size_t)B * SGRID3 * 4;
    size_t mats_bytes = (size_t)B * 72 * 4;

    if (ws_size >= tbl_bytes + mats_bytes) {
        unsigned int* tbl = (unsigned int*)d_ws;
        float* mats = (float*)((char*)d_ws + tbl_bytes);
        int cells = B * SGRID3;
        prep_kernel<<<(cells / 4 + 255) / 256, 256, 0, stream>>>(output, closest,
                                                                 tbl, mats, out, B);
        int threads = 1024;
        int ppb = threads * 8;                   // points per block
        int bpb = (N + ppb - 1) / ppb;           // blocks per batch
        sym_loss_lds<<<B * bpb, threads, 0, stream>>>(tbl, mats, points, out,
                                                      N, B, bpb, 1.0f / (float)B);
    } else {
        zero_out_kernel<<<1, 1, 0, stream>>>(out);
        int gx = (N + 1023) / 1024;
        dim3 grid(gx, B);
        sym_loss_kernel<<<grid, 256, 0, stream>>>(output, points, closest, out,
                                                  N, 1.0f / (float)B);
    }
}